// Round 1
// baseline (176.656 us; speedup 1.0000x reference)
//
#include <hip/hip_runtime.h>

#define NQ     12
#define DIM    4096          // 2^12 amplitudes
#define QDEPTH 8
#define BLOCK  1024
#define PAIRS  (DIM / 2)

// ---------------------------------------------------------------------------
// Kernel 1: simulate the 12-qubit circuit once (batch-independent: the RZ
// input encoding on |0..0> is a global phase, so probs don't depend on x).
// Statevector lives in LDS (re/im fp32, 32 KB). One block, 16 waves.
// Produces the single broadcast row: row[i] = b_up[i] + sum_j z[j]*w_up[i,j].
// ---------------------------------------------------------------------------
__global__ __launch_bounds__(BLOCK) void qnn_sim(const float* __restrict__ qw,
                                                 const float* __restrict__ w_up,
                                                 const float* __restrict__ b_up,
                                                 float* __restrict__ row) {
    __shared__ float re[DIM];
    __shared__ float im[DIM];
    __shared__ float zred[BLOCK / 64][NQ];
    __shared__ float zfin[NQ];

    const int tid = threadIdx.x;

    // init |0...0>  (global phase from input encoding dropped: |amp0|=1)
    for (int s = tid; s < DIM; s += BLOCK) { re[s] = 0.0f; im[s] = 0.0f; }
    if (tid == 0) re[0] = 1.0f;
    __syncthreads();

    for (int l = 0; l < QDEPTH; ++l) {
        const int r = (l % (NQ - 1)) + 1;   // PennyLane default entangling range
        for (int j = 0; j < NQ; ++j) {
            const float* w3 = qw + (l * NQ + j) * 3;
            const float phi = w3[0], theta = w3[1], omega = w3[2];
            float c, s_, sp, cp, sm, cm;
            sincosf(0.5f * theta, &s_, &c);
            sincosf(0.5f * (phi + omega), &sp, &cp);
            sincosf(0.5f * (phi - omega), &sm, &cm);
            // Rot = RZ(omega) RY(theta) RZ(phi)
            const float m00r =  cp * c,  m00i = -sp * c;
            const float m01r = -cm * s_, m01i = -sm * s_;
            const float m10r =  cm * s_, m10i = -sm * s_;
            const float m11r =  cp * c,  m11i =  sp * c;

            const int stride = 1 << (11 - j);   // wire 0 = MSB
            const bool last = (j == NQ - 1);    // fuse CZ diagonal into stride-1 gate

            for (int p = tid; p < PAIRS; p += BLOCK) {
                const int i0 = ((p & ~(stride - 1)) << 1) | (p & (stride - 1));
                const int i1 = i0 + stride;
                const float a0r = re[i0], a0i = im[i0];
                const float a1r = re[i1], a1i = im[i1];
                float n0r = m00r * a0r - m00i * a0i + m01r * a1r - m01i * a1i;
                float n0i = m00r * a0i + m00i * a0r + m01r * a1i + m01i * a1r;
                float n1r = m10r * a0r - m10i * a0i + m11r * a1r - m11i * a1i;
                float n1i = m10r * a0i + m10i * a0r + m11r * a1i + m11i * a1r;
                if (last) {
                    // CZ-product diagonal: sign = (-1)^popc(s & rotl12(s, r))
                    const unsigned u0 = (unsigned)i0;
                    const unsigned R0 = ((u0 << r) | (u0 >> (12 - r))) & 0xFFFu;
                    if (__popc(u0 & R0) & 1) { n0r = -n0r; n0i = -n0i; }
                    const unsigned u1 = (unsigned)i1;
                    const unsigned R1 = ((u1 << r) | (u1 >> (12 - r))) & 0xFFFu;
                    if (__popc(u1 & R1) & 1) { n1r = -n1r; n1i = -n1i; }
                }
                re[i0] = n0r; im[i0] = n0i;
                re[i1] = n1r; im[i1] = n1i;
            }
            __syncthreads();
        }
    }

    // <Z_w> = sum_s |amp_s|^2 * (1 - 2*bit_w(s))
    float zp[NQ];
#pragma unroll
    for (int w = 0; w < NQ; ++w) zp[w] = 0.0f;
    for (int s = tid; s < DIM; s += BLOCK) {
        const float p = re[s] * re[s] + im[s] * im[s];
#pragma unroll
        for (int w = 0; w < NQ; ++w)
            zp[w] += ((s >> (11 - w)) & 1) ? -p : p;
    }
    // wave64 shuffle reduce, then cross-wave via LDS
#pragma unroll
    for (int w = 0; w < NQ; ++w) {
        float v = zp[w];
        for (int off = 32; off > 0; off >>= 1) v += __shfl_down(v, off, 64);
        zp[w] = v;
    }
    const int wave = tid >> 6;
    const int lane = tid & 63;
    if (lane == 0) {
#pragma unroll
        for (int w = 0; w < NQ; ++w) zred[wave][w] = zp[w];
    }
    __syncthreads();
    if (tid < NQ) {
        float v = 0.0f;
#pragma unroll
        for (int k = 0; k < BLOCK / 64; ++k) v += zred[k][tid];
        zfin[tid] = v;
    }
    __syncthreads();

    // the single output row: row[i] = b_up[i] + sum_j z[j] * w_up[i*12+j]
    for (int i = tid; i < 784; i += BLOCK) {
        float acc = b_up[i];
#pragma unroll
        for (int j = 0; j < NQ; ++j) acc += zfin[j] * w_up[i * NQ + j];
        row[i] = acc;
    }
}

// ---------------------------------------------------------------------------
// Kernel 2: broadcast the 784-float row to all 2048 batch rows (float4).
// 784 floats = 196 float4 per row.
// ---------------------------------------------------------------------------
__global__ __launch_bounds__(256) void qnn_bcast(const float* __restrict__ row,
                                                 float* __restrict__ out) {
    const int t = threadIdx.x;
    if (t < 196) {
        const float4 v = ((const float4*)row)[t];
        ((float4*)out)[(size_t)blockIdx.x * 196 + t] = v;
    }
}

extern "C" void kernel_launch(void* const* d_in, const int* in_sizes, int n_in,
                              void* d_out, int out_size, void* d_ws, size_t ws_size,
                              hipStream_t stream) {
    // inputs: 0:x 1:w_down 2:b_down 3:w_up 4:b_up 5:qweights
    const float* w_up = (const float*)d_in[3];
    const float* b_up = (const float*)d_in[4];
    const float* qw   = (const float*)d_in[5];
    float* row = (float*)d_ws;          // 784 floats of scratch
    float* out = (float*)d_out;

    qnn_sim<<<1, BLOCK, 0, stream>>>(qw, w_up, b_up, row);
    qnn_bcast<<<2048, 256, 0, stream>>>(row, out);
}

// Round 2
// 106.533 us; speedup vs baseline: 1.6582x; 1.6582x over previous
//
#include <hip/hip_runtime.h>

#define NQ     12
#define DIM    4096
#define QDEPTH 8
#define T      256                    // 4 waves
#define STSZ   (DIM + DIM / 16)       // padded: A(i) = i + (i>>4)

__device__ __forceinline__ int A_(int i) { return i + (i >> 4); }

// ---------------------------------------------------------------------------
// One-shot 12-qubit sim (batch-independent; input encoding is a global phase).
// State float2[4096] in LDS (padded). 3 fused passes per layer (4 wires each),
// gates applied in registers. Produces row[784] = b_up + z @ w_up^T.
// ---------------------------------------------------------------------------
__global__ __launch_bounds__(T) void qnn_sim(const float* __restrict__ qw,
                                             const float* __restrict__ w_up,
                                             const float* __restrict__ b_up,
                                             float* __restrict__ row) {
    __shared__ float2 st[STSZ];
    __shared__ float4 mats[96 * 2];   // gate g: [m00r m00i m01r m01i][m10r m10i m11r m11i]
    __shared__ float  zred[T / 64][NQ];
    __shared__ float  zfin[NQ];

    const int tid = threadIdx.x;

    // phase 0: all 96 gate matrices, computed once in parallel
    if (tid < 96) {
        const float phi = qw[tid * 3 + 0], theta = qw[tid * 3 + 1], omega = qw[tid * 3 + 2];
        float c, s, sp, cp, sm, cm;
        sincosf(0.5f * theta, &s, &c);
        sincosf(0.5f * (phi + omega), &sp, &cp);
        sincosf(0.5f * (phi - omega), &sm, &cm);
        // Rot = RZ(omega) RY(theta) RZ(phi)
        mats[tid * 2 + 0] = make_float4(cp * c, -sp * c, -cm * s, -sm * s); // m00, m01
        mats[tid * 2 + 1] = make_float4(cm * s, -sm * s, cp * c, sp * c);   // m10, m11
    }
    for (int k = tid; k < STSZ; k += T) st[k] = make_float2(0.f, 0.f);
    __syncthreads();
    if (tid == 0) st[0] = make_float2(1.f, 0.f);   // A_(0) == 0
    __syncthreads();

    float2 amp[16];

#pragma unroll 1
    for (int l = 0; l < QDEPTH; ++l) {
#pragma unroll
        for (int p = 0; p < 3; ++p) {
            const int bp   = 8 - 4 * p;
            const int base = ((tid >> bp) << (bp + 4)) | (tid & ((1 << bp) - 1));

#pragma unroll
            for (int c = 0; c < 16; ++c) amp[c] = st[A_(base | (c << bp))];

            // four gates on wires 4p..4p+3; wire 4p+q toggles amp-index bit (3-q)
#pragma unroll
            for (int q = 0; q < 4; ++q) {
                const float4 Ma = mats[(l * NQ + 4 * p + q) * 2 + 0];
                const float4 Mb = mats[(l * NQ + 4 * p + q) * 2 + 1];
                const int m = 8 >> q;
#pragma unroll
                for (int c = 0; c < 16; ++c) {
                    if (c & m) continue;
                    const int c1 = c | m;
                    const float a0r = amp[c].x,  a0i = amp[c].y;
                    const float a1r = amp[c1].x, a1i = amp[c1].y;
                    amp[c].x  = Ma.x * a0r - Ma.y * a0i + Ma.z * a1r - Ma.w * a1i;
                    amp[c].y  = Ma.x * a0i + Ma.y * a0r + Ma.z * a1i + Ma.w * a1r;
                    amp[c1].x = Mb.x * a0r - Mb.y * a0i + Mb.z * a1r - Mb.w * a1i;
                    amp[c1].y = Mb.x * a0i + Mb.y * a0r + Mb.z * a1i + Mb.w * a1r;
                }
            }

            if (p == 2 && l < QDEPTH - 1) {
                // CZ entangler diagonal, range r = l+1: sign = (-1)^popc(i & rotl12(i,r))
                const int r = l + 1;
#pragma unroll
                for (int c = 0; c < 16; ++c) {
                    const unsigned i  = (unsigned)(base | c);
                    const unsigned ro = ((i << r) | (i >> (12 - r))) & 0xFFFu;
                    if (__popc(i & ro) & 1) { amp[c].x = -amp[c].x; amp[c].y = -amp[c].y; }
                }
            }
            if (!(p == 2 && l == QDEPTH - 1)) {   // last pass: keep amps in regs
#pragma unroll
                for (int c = 0; c < 16; ++c) st[A_(base | (c << bp))] = amp[c];
                __syncthreads();
            }
        }
    }

    // <Z_w> from register-resident final amps (i = tid*16 + c); layer-7 diag
    // dropped — signs don't change |amp|^2.
    float zp[NQ];
#pragma unroll
    for (int w = 0; w < NQ; ++w) zp[w] = 0.0f;
#pragma unroll
    for (int c = 0; c < 16; ++c) {
        const int i = (tid << 4) | c;
        const float pr = amp[c].x * amp[c].x + amp[c].y * amp[c].y;
#pragma unroll
        for (int w = 0; w < NQ; ++w) zp[w] += ((i >> (11 - w)) & 1) ? -pr : pr;
    }
#pragma unroll
    for (int w = 0; w < NQ; ++w) {
        float v = zp[w];
        for (int off = 32; off > 0; off >>= 1) v += __shfl_down(v, off, 64);
        zp[w] = v;
    }
    const int wave = tid >> 6, lane = tid & 63;
    if (lane == 0) {
#pragma unroll
        for (int w = 0; w < NQ; ++w) zred[wave][w] = zp[w];
    }
    __syncthreads();
    if (tid < NQ) {
        float v = 0.0f;
#pragma unroll
        for (int k = 0; k < T / 64; ++k) v += zred[k][tid];
        zfin[tid] = v;
    }
    __syncthreads();

    for (int i = tid; i < 784; i += T) {
        float acc = b_up[i];
#pragma unroll
        for (int j = 0; j < NQ; ++j) acc += zfin[j] * w_up[i * NQ + j];
        row[i] = acc;
    }
}

// ---------------------------------------------------------------------------
// Broadcast row to all 2048 batch rows (784 floats = 196 float4 per row).
// ---------------------------------------------------------------------------
__global__ __launch_bounds__(256) void qnn_bcast(const float* __restrict__ row,
                                                 float* __restrict__ out) {
    const int t = threadIdx.x;
    if (t < 196) {
        const float4 v = ((const float4*)row)[t];
        ((float4*)out)[(size_t)blockIdx.x * 196 + t] = v;
    }
}

extern "C" void kernel_launch(void* const* d_in, const int* in_sizes, int n_in,
                              void* d_out, int out_size, void* d_ws, size_t ws_size,
                              hipStream_t stream) {
    // inputs: 0:x 1:w_down 2:b_down 3:w_up 4:b_up 5:qweights
    const float* w_up = (const float*)d_in[3];
    const float* b_up = (const float*)d_in[4];
    const float* qw   = (const float*)d_in[5];
    float* row = (float*)d_ws;
    float* out = (float*)d_out;

    qnn_sim<<<1, T, 0, stream>>>(qw, w_up, b_up, row);
    qnn_bcast<<<2048, 256, 0, stream>>>(row, out);
}

// Round 3
// 106.279 us; speedup vs baseline: 1.6622x; 1.0024x over previous
//
#include <hip/hip_runtime.h>

#define NQ     12
#define DIM    4096
#define QDEPTH 8
#define T      256                    // 4 waves
#define STSZ   (DIM + (DIM / 16) * 2) // pad 2 float2 per 16 -> keeps 16B alignment

__device__ __forceinline__ int AD(int i) { return i + ((i >> 4) << 1); }

// 4 complex 2x2 gates on amp-index bits 3..0 (wire 4G+q toggles bit 3-q)
__device__ __forceinline__ void apply4(float2 amp[16], const float4* __restrict__ M) {
#pragma unroll
    for (int q = 0; q < 4; ++q) {
        const float4 Ma = M[q * 2 + 0];   // m00r m00i m01r m01i
        const float4 Mb = M[q * 2 + 1];   // m10r m10i m11r m11i
        const int m = 8 >> q;
#pragma unroll
        for (int c = 0; c < 16; ++c) {
            if (c & m) continue;
            const int c1 = c | m;
            const float a0r = amp[c].x,  a0i = amp[c].y;
            const float a1r = amp[c1].x, a1i = amp[c1].y;
            amp[c].x  = Ma.x * a0r - Ma.y * a0i + Ma.z * a1r - Ma.w * a1i;
            amp[c].y  = Ma.x * a0i + Ma.y * a0r + Ma.z * a1i + Ma.w * a1r;
            amp[c1].x = Mb.x * a0r - Mb.y * a0i + Mb.z * a1r - Mb.w * a1i;
            amp[c1].y = Mb.x * a0i + Mb.y * a0r + Mb.z * a1i + Mb.w * a1r;
        }
    }
}

// One LDS pass on wire-group G = (8-BP)/4 (bits BP+3..BP): gates of layer l1,
// optional CZ diagonal of layer d, optional gates of layer l2, optional store.
template <int BP>
__device__ __forceinline__ void do_pass(float2* __restrict__ st,
                                        const float4* __restrict__ mats,
                                        int tid, int l1, int d, int l2,
                                        bool store, float2 amp[16]) {
    constexpr int G = (8 - BP) / 4;
    const int base = ((tid >> BP) << (BP + 4)) | (tid & ((1 << BP) - 1));

    if (BP == 0) {
        const float4* p = (const float4*)&st[AD(base)];
#pragma unroll
        for (int k = 0; k < 8; ++k) {
            const float4 v = p[k];
            amp[2 * k]     = make_float2(v.x, v.y);
            amp[2 * k + 1] = make_float2(v.z, v.w);
        }
    } else {
#pragma unroll
        for (int c = 0; c < 16; ++c) amp[c] = st[AD(base | (c << BP))];
    }

    apply4(amp, mats + (l1 * NQ + 4 * G) * 2);

    if (d >= 0) {
        const int r = d + 1;   // CZ range for layer d (d <= 6 here)
#pragma unroll
        for (int c = 0; c < 16; ++c) {
            const unsigned i  = (unsigned)(base | (c << BP));
            const unsigned ro = ((i << r) | (i >> (12 - r))) & 0xFFFu;
            if (__popc(i & ro) & 1) { amp[c].x = -amp[c].x; amp[c].y = -amp[c].y; }
        }
        apply4(amp, mats + (l2 * NQ + 4 * G) * 2);
    }

    if (store) {
        if (BP == 0) {
            float4* p = (float4*)&st[AD(base)];
#pragma unroll
            for (int k = 0; k < 8; ++k)
                p[k] = make_float4(amp[2 * k].x, amp[2 * k].y,
                                   amp[2 * k + 1].x, amp[2 * k + 1].y);
        } else {
#pragma unroll
            for (int c = 0; c < 16; ++c) st[AD(base | (c << BP))] = amp[c];
        }
    }
}

struct Pass { signed char g, l1, d, l2; };

__global__ __launch_bounds__(T) void qnn_sim(const float* __restrict__ qw,
                                             const float* __restrict__ w_up,
                                             const float* __restrict__ b_up,
                                             float* __restrict__ row) {
    __shared__ float2 st[STSZ];
    __shared__ float4 mats[96 * 2];
    __shared__ float  zred[T / 64][NQ];
    __shared__ float  zfin[NQ];

    const int tid = threadIdx.x;

    if (tid < 96) {
        const float phi = qw[tid * 3 + 0], theta = qw[tid * 3 + 1], omega = qw[tid * 3 + 2];
        float c, s, sp, cp, sm, cm;
        sincosf(0.5f * theta, &s, &c);
        sincosf(0.5f * (phi + omega), &sp, &cp);
        sincosf(0.5f * (phi - omega), &sm, &cm);
        mats[tid * 2 + 0] = make_float4(cp * c, -sp * c, -cm * s, -sm * s);
        mats[tid * 2 + 1] = make_float4(cm * s, -sm * s, cp * c, sp * c);
    }
    for (int k = tid; k < STSZ; k += T) st[k] = make_float2(0.f, 0.f);
    __syncthreads();
    if (tid == 0) st[0] = make_float2(1.f, 0.f);
    __syncthreads();

    // Layer group orders rotate (ABC, CAB, BCA, ...) so the last group of
    // layer l == first group of layer l+1 -> merged pass with CZ diag fused.
    static const Pass P[16] = {
        {0, 0, -1, -1}, {1, 0, -1, -1}, {2, 0, 0, 1},
        {0, 1, -1, -1}, {1, 1, 1, 2},
        {2, 2, -1, -1}, {0, 2, 2, 3},
        {1, 3, -1, -1}, {2, 3, 3, 4},
        {0, 4, -1, -1}, {1, 4, 4, 5},
        {2, 5, -1, -1}, {0, 5, 5, 6},
        {1, 6, -1, -1}, {2, 6, 6, 7},
        {0, 7, -1, -1},
    };

    float2 amp[16];
#pragma unroll 1
    for (int p = 0; p < 16; ++p) {
        const int g = P[p].g, l1 = P[p].l1, d = P[p].d, l2 = P[p].l2;
        if (g == 0)      do_pass<8>(st, mats, tid, l1, d, l2, true, amp);
        else if (g == 1) do_pass<4>(st, mats, tid, l1, d, l2, true, amp);
        else             do_pass<0>(st, mats, tid, l1, d, l2, true, amp);
        __syncthreads();
    }
    // final pass: B7 (wires 4-7), keep amps in registers; layer-7 CZ diag
    // dropped (signs don't change |amp|^2)
    do_pass<4>(st, mats, tid, 7, -1, -1, false, amp);

    const int fb = ((tid >> 4) << 8) | (tid & 15);
    float zp[NQ];
#pragma unroll
    for (int w = 0; w < NQ; ++w) zp[w] = 0.0f;
#pragma unroll
    for (int c = 0; c < 16; ++c) {
        const int i = fb | (c << 4);
        const float pr = amp[c].x * amp[c].x + amp[c].y * amp[c].y;
#pragma unroll
        for (int w = 0; w < NQ; ++w) zp[w] += ((i >> (11 - w)) & 1) ? -pr : pr;
    }
#pragma unroll
    for (int w = 0; w < NQ; ++w) {
        float v = zp[w];
        for (int off = 32; off > 0; off >>= 1) v += __shfl_down(v, off, 64);
        zp[w] = v;
    }
    const int wave = tid >> 6, lane = tid & 63;
    if (lane == 0) {
#pragma unroll
        for (int w = 0; w < NQ; ++w) zred[wave][w] = zp[w];
    }
    __syncthreads();
    if (tid < NQ) {
        float v = 0.0f;
#pragma unroll
        for (int k = 0; k < T / 64; ++k) v += zred[k][tid];
        zfin[tid] = v;
    }
    __syncthreads();

    for (int i = tid; i < 784; i += T) {
        float acc = b_up[i];
#pragma unroll
        for (int j = 0; j < NQ; ++j) acc += zfin[j] * w_up[i * NQ + j];
        row[i] = acc;
    }
}

__global__ __launch_bounds__(256) void qnn_bcast(const float* __restrict__ row,
                                                 float* __restrict__ out) {
    const int t = threadIdx.x;
    if (t < 196) {
        const float4 v = ((const float4*)row)[t];
        ((float4*)out)[(size_t)blockIdx.x * 196 + t] = v;
    }
}

extern "C" void kernel_launch(void* const* d_in, const int* in_sizes, int n_in,
                              void* d_out, int out_size, void* d_ws, size_t ws_size,
                              hipStream_t stream) {
    // inputs: 0:x 1:w_down 2:b_down 3:w_up 4:b_up 5:qweights
    const float* w_up = (const float*)d_in[3];
    const float* b_up = (const float*)d_in[4];
    const float* qw   = (const float*)d_in[5];
    float* row = (float*)d_ws;
    float* out = (float*)d_out;

    qnn_sim<<<1, T, 0, stream>>>(qw, w_up, b_up, row);
    qnn_bcast<<<2048, 256, 0, stream>>>(row, out);
}